// Round 4
// baseline (157.627 us; speedup 1.0000x reference)
//
#include <hip/hip_runtime.h>
#include <stdint.h>

#define BATCH 2
#define NPTS  2048
#define CIN   64
#define COUT  64
#define NCELL 9

// knorm = 315 / (64*pi*0.1^9)
#define KNORM 1.5666851e9f
#define R2 0.01f

typedef __attribute__((address_space(3))) uint8_t        lds_t;
typedef const __attribute__((address_space(1))) uint8_t  glb_t;

static __device__ __forceinline__ float rdlane(float v, int l) {
    return __int_as_float(__builtin_amdgcn_readlane(__float_as_int(v), l));
}

// ---------------------------------------------------------------------------
// Workspace (floats):
//   dcoefT [B][N][64]        262144   (j-major: 64j x 64c tiles contiguous)
//   posT   [B][N] float2       8192
//   W2T    [9][64c][64o]      36864
//   field  [B][N][9][64c]   2359296   (per-i contiguous 2304 B)
// ---------------------------------------------------------------------------

// Prep: dcoefT, posT, W2T, and out = bias (atomic accumulation target).
__global__ __launch_bounds__(256) void prep_kernel(
    const float* __restrict__ locs, const float* __restrict__ data,
    const float* __restrict__ density, const float* __restrict__ weight,
    const float* __restrict__ bias,
    float* __restrict__ dcoefT, float2* __restrict__ posT,
    float* __restrict__ W2T, float* __restrict__ out)
{
    const int tid = threadIdx.x, lane = tid & 63, wid = tid >> 6;
    const int g = blockIdx.x;
    if (g < BATCH * (NPTS / 64)) {
        __shared__ float tile[64 * 65];
        const int b = g >> 5, j0 = (g & 31) * 64;
        const int j = j0 + lane;
        float im = locs[(b * NPTS + j) * 3 + 2];
        float de = density[b * NPTS + j];
        float coef = 1.0f / (im * de);
        if (wid == 0)
            posT[b * NPTS + j] =
                make_float2(locs[(b * NPTS + j) * 3 + 0], locs[(b * NPTS + j) * 3 + 1]);
#pragma unroll
        for (int it = 0; it < 16; it++) {
            int c = it * 4 + wid;
            tile[c * 65 + lane] = data[(b * CIN + c) * NPTS + j] * coef;
        }
        __syncthreads();
#pragma unroll
        for (int it = 0; it < 16; it++) {
            int jr = it * 4 + wid;
            dcoefT[(b * NPTS + j0 + jr) * 64 + lane] = tile[lane * 65 + jr];
        }
    } else if (g < BATCH * (NPTS / 64) + NCELL) {
        const int k = g - BATCH * (NPTS / 64);
        for (int e = tid; e < 64 * 64; e += 256) {
            int c = e >> 6, o = e & 63;
            W2T[(k * 64 + c) * 64 + o] = weight[(o * CIN + c) * NCELL + k];
        }
    } else {
        // out[b][o][i] = bias[o]; 128 blocks x 512 float4
        const int gb = g - (BATCH * (NPTS / 64) + NCELL);
#pragma unroll
        for (int r = 0; r < 2; r++) {
            int e4 = (gb * 512 + r * 256 + tid) * 4;
            float bv = bias[(e4 >> 11) & 63];
            *(float4*)(out + e4) = make_float4(bv, bv, bv, bv);
        }
    }
}

// ---------------------------------------------------------------------------
// Field: field[b,i,k,c] = sum_j w_k(i,j) * dcoef[b,c,j]
// 8 waves/block, one i per wave, lane = channel (phase 2) / j (phase 1).
// dcoefT chunks double-buffered in LDS via global_load_lds; w broadcast
// via v_readlane (VALU pipe); dc via single conflict-free ds_read_b32.
// ---------------------------------------------------------------------------
__global__ __launch_bounds__(512) void field_kernel(
    const float2* __restrict__ posT, const float* __restrict__ dcoefT,
    float* __restrict__ field)
{
    __shared__ float dcs[2][64 * 64];        // dbuf: [jj][c], contiguous

    const int tid  = threadIdx.x;
    const int lane = tid & 63;
    const int wid  = tid >> 6;
    const int gi   = blockIdx.x * 8 + wid;   // global i over B*N
    const int b    = gi >> 11;

    const float2 pi = posT[gi];
    const float* dcb = dcoefT + (size_t)b * NPTS * 64;

    float f[NCELL];
#pragma unroll
    for (int k = 0; k < NCELL; k++) f[k] = 0.0f;

    // preload chunk 0 into buf 0 (2 x 1KB segments per wave)
#pragma unroll
    for (int s = 0; s < 2; s++) {
        int seg = wid * 2 + s;
        __builtin_amdgcn_global_load_lds((glb_t*)(dcb + seg * 256 + lane * 4),
                                         (lds_t*)(&dcs[0][seg * 256]), 16, 0, 0);
    }

    for (int n = 0; n < NPTS / 64; n++) {
        // ---- phase 1: w for jj = lane (no LDS) -----------------------------
        float2 pj = posT[b * NPTS + n * 64 + lane];
        float dx = pi.x - pj.x;
        float dy = pi.y - pj.y;

        float ax0 = dx - 0.05f, ax1 = dx, ax2 = dx + 0.05f;
        float ay0 = dy - 0.05f, ay1 = dy, ay2 = dy + 0.05f;
        float ty0 = fmaf(-ay0, ay0, R2);
        float ty1 = fmaf(-ay1, ay1, R2);
        float ty2 = fmaf(-ay2, ay2, R2);

        float t[NCELL];
        t[0] = fmaf(-ax0, ax0, ty0);
        t[1] = fmaf(-ax0, ax0, ty1);
        t[2] = fmaf(-ax0, ax0, ty2);
        t[3] = fmaf(-ax1, ax1, ty0);
        t[4] = fmaf(-ax1, ax1, ty1);
        t[5] = fmaf(-ax1, ax1, ty2);
        t[6] = fmaf(-ax2, ax2, ty0);
        t[7] = fmaf(-ax2, ax2, ty1);
        t[8] = fmaf(-ax2, ax2, ty2);

        float wv[NCELL];
        float tmax = t[0];
#pragma unroll
        for (int k = 0; k < NCELL; k++) {
            float mt = fmaxf(t[k], 0.0f);
            wv[k] = mt * mt * (mt * KNORM);
            if (k) tmax = fmaxf(tmax, t[k]);
        }
        unsigned long long m = __ballot(tmax > 0.0f);

        __syncthreads();          // chunk n DMA complete, buf (n-1)&1 free

        // ---- issue DMA for chunk n+1 into the other buffer -----------------
        if (n + 1 < NPTS / 64) {
            const float* src = dcb + (n + 1) * 64 * 64;
#pragma unroll
            for (int s = 0; s < 2; s++) {
                int seg = wid * 2 + s;
                __builtin_amdgcn_global_load_lds(
                    (glb_t*)(src + seg * 256 + lane * 4),
                    (lds_t*)(&dcs[(n + 1) & 1][seg * 256]), 16, 0, 0);
            }
        }

        // ---- phase 2: ctz loop, 2-deep dc prefetch -------------------------
        const float* dbuf = dcs[n & 1];
        if (m) {
            int j0 = __builtin_ctzll(m); m &= m - 1;
            float d0 = dbuf[j0 * 64 + lane];
            int j1 = 0; float d1 = 0.0f; bool has1 = false;
            if (m) {
                j1 = __builtin_ctzll(m); m &= m - 1;
                d1 = dbuf[j1 * 64 + lane]; has1 = true;
            }
            while (m) {
                int j2 = __builtin_ctzll(m); m &= m - 1;
                float d2 = dbuf[j2 * 64 + lane];
#pragma unroll
                for (int k = 0; k < NCELL; k++)
                    f[k] = fmaf(rdlane(wv[k], j0), d0, f[k]);
                j0 = j1; d0 = d1; j1 = j2; d1 = d2;
            }
#pragma unroll
            for (int k = 0; k < NCELL; k++)
                f[k] = fmaf(rdlane(wv[k], j0), d0, f[k]);
            if (has1) {
#pragma unroll
                for (int k = 0; k < NCELL; k++)
                    f[k] = fmaf(rdlane(wv[k], j1), d1, f[k]);
            }
        }
    }

    // field[b][i][k][c]: 9 x 256 B contiguous stores
    float* fb = field + (size_t)gi * NCELL * 64 + lane;
#pragma unroll
    for (int k = 0; k < NCELL; k++) fb[k * 64] = f[k];
}

// ---------------------------------------------------------------------------
// Out: split-K over cells, atomicAdd into bias-initialized out.
// Grid (64 i-tiles, 9 cells) x 256 thr. Wave w owns o = w*16..w*16+15
// (weight reads wave-uniform -> s_load), lane = i (coalesced field/out).
// ---------------------------------------------------------------------------
__global__ __launch_bounds__(256) void out_gemm(
    const float* __restrict__ field, const float* __restrict__ W2T,
    float* __restrict__ out)
{
    __shared__ float Ft[64 * 65];            // [i][c], padded

    const int tid  = threadIdx.x;
    const int lane = tid & 63;
    const int w    = tid >> 6;
    const int bx   = blockIdx.x;
    const int k    = blockIdx.y;
    const int b    = bx >> 5;
    const int i0   = (bx & 31) * 64;

    {
        int row = tid >> 2, q = tid & 3;
        const float* fr = field + ((size_t)(b * NPTS + i0 + row) * NCELL + k) * 64;
#pragma unroll
        for (int s = 0; s < 4; s++)
            *(float4*)(Ft + row * 65 + q * 16 + s * 4) =
                *(const float4*)(fr + q * 16 + s * 4);
    }
    __syncthreads();

    float acc[16];
#pragma unroll
    for (int t = 0; t < 16; t++) acc[t] = 0.0f;

    const float* wk = W2T + k * 4096 + w * 16;
#pragma unroll 4
    for (int c = 0; c < 64; c++) {
        float fv = Ft[lane * 65 + c];
#pragma unroll
        for (int t = 0; t < 16; t++)
            acc[t] = fmaf(wk[c * 64 + t], fv, acc[t]);
    }

    float* ob = out + ((size_t)b * COUT + w * 16) * NPTS + i0 + lane;
#pragma unroll
    for (int t = 0; t < 16; t++)
        unsafeAtomicAdd(ob + t * NPTS, acc[t]);
}

extern "C" void kernel_launch(void* const* d_in, const int* in_sizes, int n_in,
                              void* d_out, int out_size, void* d_ws, size_t ws_size,
                              hipStream_t stream)
{
    const float* locs    = (const float*)d_in[0];
    const float* data    = (const float*)d_in[1];
    const float* density = (const float*)d_in[2];
    const float* weight  = (const float*)d_in[3];
    const float* bias    = (const float*)d_in[4];
    float* out = (float*)d_out;

    float*  dcoefT = (float*)d_ws;                            // 262144
    float2* posT   = (float2*)(dcoefT + BATCH * NPTS * 64);   // 8192 floats
    float*  W2T    = (float*)(posT + BATCH * NPTS);           // 36864
    float*  field  = W2T + NCELL * 64 * 64;                   // 2359296

    const int nprep = BATCH * (NPTS / 64) + NCELL + 128;      // 64 + 9 + 128
    prep_kernel<<<nprep, 256, 0, stream>>>(
        locs, data, density, weight, bias, dcoefT, posT, W2T, out);
    field_kernel<<<BATCH * NPTS / 8, 512, 0, stream>>>(posT, dcoefT, field);
    out_gemm<<<dim3(BATCH * (NPTS / 64), NCELL), 256, 0, stream>>>(field, W2T, out);
}

// Round 5
// 129.328 us; speedup vs baseline: 1.2188x; 1.2188x over previous
//
#include <hip/hip_runtime.h>
#include <hip/hip_bf16.h>
#include <stdint.h>

#define BATCH 2
#define NPTS  2048
#define CIN   64
#define COUT  64
#define NCELL 9

// knorm = 315 / (64*pi*0.1^9)
#define KNORM 1.5666851e9f
#define R2 0.01f

typedef __attribute__((ext_vector_type(8))) __bf16 bf16x8;
typedef __attribute__((ext_vector_type(4))) float  f32x4;

union B8 { uint4 u; bf16x8 v; };

static __device__ __forceinline__ unsigned pk2(float a, float b) {
    union { __hip_bfloat162 h; unsigned u; } cv;
    cv.h = __float22bfloat162_rn(make_float2(a, b));
    return cv.u;
}

// ---------------------------------------------------------------------------
// Workspace:
//   posT  float2[B*N]                    32 KB
//   dC    bf16  [B][C][N]  (c-major)    512 KB   -- GEMM1 B-matrix source
//   WB    bf16  [9][2ks][4nb][64][8]     72 KB   -- GEMM2 B pre-swizzled frags
// ---------------------------------------------------------------------------

__global__ __launch_bounds__(256) void prep_kernel(
    const float* __restrict__ locs, const float* __restrict__ data,
    const float* __restrict__ density, const float* __restrict__ weight,
    float2* __restrict__ posT, uint16_t* __restrict__ dC,
    uint16_t* __restrict__ WB)
{
    const int tid = threadIdx.x;
    const int g = blockIdx.x;
    if (g < 256) {
        // dcoef bf16: dC[b][c][j] = data[b][c][j] / (invmass[b][j]*density[b][j])
        int e = g * 256 + tid;             // 0..65535, 4 j each
        int j4 = e & 511, bc = e >> 9;     // bc = b*64 + c
        int b = bc >> 6;
        float4 dv = *(const float4*)(data + bc * 2048 + j4 * 4);
        float4 de = *(const float4*)(density + b * 2048 + j4 * 4);
        int jb = (b * 2048 + j4 * 4) * 3 + 2;
        float m0 = locs[jb], m1 = locs[jb + 3], m2 = locs[jb + 6], m3 = locs[jb + 9];
        float v0 = dv.x / (m0 * de.x);
        float v1 = dv.y / (m1 * de.y);
        float v2 = dv.z / (m2 * de.z);
        float v3 = dv.w / (m3 * de.w);
        *(uint2*)(dC + bc * 2048 + j4 * 4) = make_uint2(pk2(v0, v1), pk2(v2, v3));
    } else if (g < 272) {
        int jj = (g - 256) * 256 + tid;    // 0..4095 == b*2048 + j
        posT[jj] = make_float2(locs[jj * 3], locs[jj * 3 + 1]);
    } else {
        // WB: B-fragment order for GEMM2. B[k=c][n=o], frag elem jj:
        // c = ks*32 + quad*8 + jj, o = nb*16 + (lane&15)
        int cell = g - 272;
        for (int it = 0; it < 16; it++) {
            int e = it * 256 + tid;        // 0..4095
            int ks = e >> 11, nb = (e >> 9) & 3, lane = (e >> 3) & 63, jj = e & 7;
            int o = nb * 16 + (lane & 15);
            int c = ks * 32 + ((lane >> 4) & 3) * 8 + jj;
            union { __hip_bfloat16 h; uint16_t u; } cv;
            cv.h = __float2bfloat16(weight[(o * 64 + c) * 9 + cell]);
            WB[cell * 4096 + e] = cv.u;
        }
    }
}

// ---------------------------------------------------------------------------
// Fused conv: one 16-i tile per block (4 waves).
// GEMM1 (dense, MFMA 16x16x32 bf16): field[i][c] = sum_j w_k(i,j)*dcoef[j][c],
//   per cell. w computed per lane directly in A-frag layout
//   (m = lane&15 = i, k = quad*8 + jj = j). Cells split 3/2/2/2 over waves.
// GEMM2: out[i][o] = bias[o] + sum_{cell,c} field[i][c] * W[c][o], wave = o-block.
// ---------------------------------------------------------------------------
__global__ __launch_bounds__(256) void conv_kernel(
    const float2* __restrict__ posT, const uint16_t* __restrict__ dC,
    const uint16_t* __restrict__ WB, const float* __restrict__ bias,
    float* __restrict__ out)
{
    __shared__ uint32_t db[2][64 * 20];    // dcoef chunk [c][32j] bf16, 80B rows
    __shared__ float    pj2[2][64];        // 32 float2 of j-positions
    __shared__ float    ft[NCELL * 16 * 68]; // field tile [cell][i][c], pad 68
    __shared__ float    ot[64 * 20];       // out tile [o][i], pad 20

    const int tid  = threadIdx.x;
    const int lane = tid & 63;
    const int wid  = tid >> 6;
    const int cl   = lane & 15;
    const int quad = lane >> 4;
    const int b    = blockIdx.x >> 7;
    const int i0   = (blockIdx.x & 127) * 16;

    // cells per wave: wid0:{0,1,2} wid1:{3,4} wid2:{5,6} wid3:{7,8}
    const int c0 = (wid == 0) ? 0 : (1 + wid * 2);
    const int nc = (wid == 0) ? 3 : 2;
    float oxr[3], oyr[3];
#pragma unroll
    for (int ci = 0; ci < 3; ci++) {
        int k = c0 + (ci < nc ? ci : 0);
        oxr[ci] = (float)(k / 3 - 1) * 0.05f;
        oyr[ci] = (float)(k % 3 - 1) * 0.05f;
    }

    const float2 pI = posT[b * 2048 + i0 + cl];

    f32x4 acc[3][4];
#pragma unroll
    for (int ci = 0; ci < 3; ci++)
#pragma unroll
        for (int nb = 0; nb < 4; nb++) acc[ci][nb] = (f32x4){0.f, 0.f, 0.f, 0.f};

    const int sc = tid >> 2, sp = tid & 3;   // staging row / 16B part

    // ---- stage chunk 0 -----------------------------------------------------
    {
        uint4 v = *(const uint4*)(dC + (b * 64 + sc) * 2048 + sp * 8);
        *(uint4*)&db[0][sc * 20 + sp * 4] = v;
        if (tid < 16)
            ((float4*)&pj2[0][0])[tid] = ((const float4*)(posT + b * 2048))[tid];
    }

    for (int n = 0; n < 64; n++) {
        __syncthreads();                     // chunk n staged
        if (n < 63) {                        // stage n+1 into other buffer
            int nb1 = (n + 1) & 1;
            uint4 v = *(const uint4*)(dC + (b * 64 + sc) * 2048 + (n + 1) * 32 + sp * 8);
            *(uint4*)&db[nb1][sc * 20 + sp * 4] = v;
            if (tid < 16)
                ((float4*)&pj2[nb1][0])[tid] =
                    ((const float4*)(posT + b * 2048 + (n + 1) * 32))[tid];
        }
        const int buf = n & 1;

        // B-frags (shared by all cells): dcoef[j=quad*8..+7][c=nb*16+cl]
        B8 bf[4];
#pragma unroll
        for (int nb = 0; nb < 4; nb++)
            bf[nb].u = *(uint4*)&db[buf][(nb * 16 + cl) * 20 + quad * 4];

        // my 8 pair geometries
        const float4* pb = (const float4*)&pj2[buf][quad * 16];
        float4 q0 = pb[0], q1 = pb[1], q2 = pb[2], q3 = pb[3];
        float dxv[8], dyv[8];
        dxv[0] = pI.x - q0.x; dyv[0] = pI.y - q0.y;
        dxv[1] = pI.x - q0.z; dyv[1] = pI.y - q0.w;
        dxv[2] = pI.x - q1.x; dyv[2] = pI.y - q1.y;
        dxv[3] = pI.x - q1.z; dyv[3] = pI.y - q1.w;
        dxv[4] = pI.x - q2.x; dyv[4] = pI.y - q2.y;
        dxv[5] = pI.x - q2.z; dyv[5] = pI.y - q2.w;
        dxv[6] = pI.x - q3.x; dyv[6] = pI.y - q3.y;
        dxv[7] = pI.x - q3.z; dyv[7] = pI.y - q3.w;

#pragma unroll
        for (int ci = 0; ci < 3; ci++) {
            if (ci < nc) {                   // wave-uniform
                float ox = oxr[ci], oy = oyr[ci];
                float w[8];
#pragma unroll
                for (int p = 0; p < 8; p++) {
                    float ax = dxv[p] + ox;
                    float sx = fmaf(-ax, ax, R2);   // CSE across cells w/ same ox
                    float ay = dyv[p] + oy;
                    float t  = fmaf(-ay, ay, sx);
                    float mt = fmaxf(t, 0.0f);
                    w[p] = (mt * mt) * (mt * KNORM);
                }
                B8 af;
                af.u = make_uint4(pk2(w[0], w[1]), pk2(w[2], w[3]),
                                  pk2(w[4], w[5]), pk2(w[6], w[7]));
#pragma unroll
                for (int nb = 0; nb < 4; nb++)
                    acc[ci][nb] = __builtin_amdgcn_mfma_f32_16x16x32_bf16(
                        af.v, bf[nb].v, acc[ci][nb], 0, 0, 0);
            }
        }
    }

    // ---- C-frags -> ft[cell][i][c]  (D: row=i=quad*4+r, col=c=nb*16+cl) ----
#pragma unroll
    for (int ci = 0; ci < 3; ci++) {
        if (ci < nc) {
            int k = c0 + ci;
#pragma unroll
            for (int nb = 0; nb < 4; nb++)
#pragma unroll
                for (int r = 0; r < 4; r++)
                    ft[(k * 16 + quad * 4 + r) * 68 + nb * 16 + cl] = acc[ci][nb][r];
        }
    }
    __syncthreads();

    // ---- GEMM2: wave wid = o-block; A = field (m=i=cl, k=c=quad*8+jj) ------
    float bv = bias[wid * 16 + cl];
    f32x4 acc2 = {bv, bv, bv, bv};
#pragma unroll
    for (int k = 0; k < NCELL; k++)
#pragma unroll
        for (int ks = 0; ks < 2; ks++) {
            const float* fp = &ft[(k * 16 + cl) * 68 + ks * 32 + quad * 8];
            float4 lo = *(const float4*)fp;
            float4 hi = *(const float4*)(fp + 4);
            B8 af;
            af.u = make_uint4(pk2(lo.x, lo.y), pk2(lo.z, lo.w),
                              pk2(hi.x, hi.y), pk2(hi.z, hi.w));
            B8 wf;
            wf.u = *(const uint4*)(WB + k * 4096 + (ks * 4 + wid) * 512 + lane * 8);
            acc2 = __builtin_amdgcn_mfma_f32_16x16x32_bf16(af.v, wf.v, acc2, 0, 0, 0);
        }

    // D: row=i=quad*4+r, col=o'=cl  ->  ot[o][i]
    *(float4*)&ot[(wid * 16 + cl) * 20 + quad * 4] =
        make_float4(acc2[0], acc2[1], acc2[2], acc2[3]);
    __syncthreads();

    // coalesced store: out[b][o][i0 + 0..15]
    {
        int o = tid >> 2, part = tid & 3;
        *(float4*)(out + (b * 64 + o) * 2048 + i0 + part * 4) =
            *(float4*)&ot[o * 20 + part * 4];
    }
}

extern "C" void kernel_launch(void* const* d_in, const int* in_sizes, int n_in,
                              void* d_out, int out_size, void* d_ws, size_t ws_size,
                              hipStream_t stream)
{
    const float* locs    = (const float*)d_in[0];   // (B, N, 3)
    const float* data    = (const float*)d_in[1];   // (B, CIN, N)
    const float* density = (const float*)d_in[2];   // (B, N)
    const float* weight  = (const float*)d_in[3];   // (COUT, CIN, 9)
    const float* bias    = (const float*)d_in[4];   // (COUT,)
    float* out = (float*)d_out;                     // (B, COUT, N)

    float2*   posT = (float2*)d_ws;                            // 32768 B
    uint16_t* dC   = (uint16_t*)((char*)d_ws + 32768);         // 524288 B
    uint16_t* WB   = (uint16_t*)((char*)d_ws + 32768 + 524288);// 73728 B

    prep_kernel<<<256 + 16 + NCELL, 256, 0, stream>>>(
        locs, data, density, weight, posT, dC, WB);
    conv_kernel<<<BATCH * NPTS / 16, 256, 0, stream>>>(posT, dC, WB, bias, out);
}

// Round 6
// 91.829 us; speedup vs baseline: 1.7165x; 1.4084x over previous
//
#include <hip/hip_runtime.h>
#include <hip/hip_bf16.h>
#include <stdint.h>

#define BATCH 2
#define NPTS  2048
#define CIN   64
#define COUT  64
#define NCELL 9

// knorm = 315 / (64*pi*0.1^9)
#define KNORM 1.5666851e9f
#define R2 0.01f

typedef __attribute__((ext_vector_type(8))) __bf16 bf16x8;
typedef __attribute__((ext_vector_type(4))) float  f32x4;

union B8 { uint4 u; bf16x8 v; };

typedef __attribute__((address_space(3))) uint8_t        lds_t;
typedef const __attribute__((address_space(1))) uint8_t  glb_t;

static __device__ __forceinline__ unsigned pk2(float a, float b) {
    union { __hip_bfloat162 h; unsigned u; } cv;
    cv.h = __float22bfloat162_rn(make_float2(a, b));
    return cv.u;
}

// ---------------------------------------------------------------------------
// Workspace:
//   posT  float2[B*N]                    32 KB
//   dC    bf16  [B][C][N]  (c-major)    512 KB
//   WB    bf16  [9][2ks][4ob][64][8]     72 KB   -- GEMM2 B pre-swizzled frags
// ---------------------------------------------------------------------------

__global__ __launch_bounds__(256) void prep_kernel(
    const float* __restrict__ locs, const float* __restrict__ data,
    const float* __restrict__ density, const float* __restrict__ weight,
    const float* __restrict__ bias,
    float2* __restrict__ posT, uint16_t* __restrict__ dC,
    uint16_t* __restrict__ WB, float* __restrict__ out)
{
    const int tid = threadIdx.x;
    const int g = blockIdx.x;
    if (g < 256) {
        // dC[b][c][j] = bf16( data / (invmass * density) )
        int e = g * 256 + tid;             // 4 j each
        int j4 = e & 511, bc = e >> 9;
        int b = bc >> 6;
        float4 dv = *(const float4*)(data + bc * 2048 + j4 * 4);
        float4 de = *(const float4*)(density + b * 2048 + j4 * 4);
        int jb = (b * 2048 + j4 * 4) * 3 + 2;
        float m0 = locs[jb], m1 = locs[jb + 3], m2 = locs[jb + 6], m3 = locs[jb + 9];
        float v0 = dv.x / (m0 * de.x);
        float v1 = dv.y / (m1 * de.y);
        float v2 = dv.z / (m2 * de.z);
        float v3 = dv.w / (m3 * de.w);
        *(uint2*)(dC + bc * 2048 + j4 * 4) = make_uint2(pk2(v0, v1), pk2(v2, v3));
    } else if (g < 272) {
        int jj = (g - 256) * 256 + tid;
        posT[jj] = make_float2(locs[jj * 3], locs[jj * 3 + 1]);
    } else if (g < 272 + NCELL) {
        // WB[cell][ks][ob][lane][jj]: o = ob*16 + (lane&15), c = ks*32 + quad*8 + jj
        int cell = g - 272;
        for (int it = 0; it < 16; it++) {
            int e = it * 256 + tid;
            int ks = e >> 11, ob = (e >> 9) & 3, lane = (e >> 3) & 63, jj = e & 7;
            int o = ob * 16 + (lane & 15);
            int c = ks * 32 + ((lane >> 4) & 3) * 8 + jj;
            union { __hip_bfloat16 h; uint16_t u; } cv;
            cv.h = __float2bfloat16(weight[(o * 64 + c) * 9 + cell]);
            WB[cell * 4096 + e] = cv.u;
        }
    } else {
        // out[b][o][i] = bias[o]  (atomic accumulation target)
        const int gb = g - (272 + NCELL);
#pragma unroll
        for (int r = 0; r < 2; r++) {
            int e4 = (gb * 512 + r * 256 + tid) * 4;
            float bv = bias[(e4 >> 11) & 63];
            *(float4*)(out + e4) = make_float4(bv, bv, bv, bv);
        }
    }
}

// ---------------------------------------------------------------------------
// Fused conv, j-split x4: block = 16-i tile x 512-j range (16 chunks of 32 j).
// GEMM1: w in A-frag registers (m=lane&15=i, k=quad*8+jj=j), dcoef B-frags
// from LDS (global_load_lds staged, unpadded - DMA layout == read layout).
// Cells split 3/2/2/2 over 4 waves. GEMM2 per-wave on its own cells via a
// private LDS transpose slice; block-reduce + fp32 atomics into out.
// ---------------------------------------------------------------------------
__global__ __launch_bounds__(256, 4) void conv_kernel(
    const float2* __restrict__ posT, const uint16_t* __restrict__ dC,
    const uint16_t* __restrict__ WB, float* __restrict__ out)
{
    __shared__ uint16_t db[2][2048];          // 2 x 4KB: [c][32j] bf16, unpadded
    __shared__ float    sft[4 * 16 * 68];     // per-wave transpose/reduce slices

    const int tid  = threadIdx.x;
    const int lane = tid & 63;
    const int wid  = tid >> 6;
    const int cl   = lane & 15;
    const int quad = lane >> 4;
    const int bx   = blockIdx.x;
    const int b    = bx >> 9;
    const int i0   = ((bx >> 2) & 127) * 16;
    const int jh   = bx & 3;                  // j-range [jh*512, jh*512+512)
    const int jb0  = jh * 512;

    // cells per wave: wid0:{0,1,2} wid1:{3,4} wid2:{5,6} wid3:{7,8}
    const int c0 = (wid == 0) ? 0 : (1 + wid * 2);
    const int nc = (wid == 0) ? 3 : 2;
    float oxr[3], oyr[3];
#pragma unroll
    for (int ci = 0; ci < 3; ci++) {
        int k = c0 + (ci < nc ? ci : 0);
        oxr[ci] = (float)(k / 3 - 1) * 0.05f;
        oyr[ci] = (float)(k % 3 - 1) * 0.05f;
    }

    const float2 pI = posT[b * 2048 + i0 + cl];

    f32x4 acc[3][4];
#pragma unroll
    for (int ci = 0; ci < 3; ci++)
#pragma unroll
        for (int nb = 0; nb < 4; nb++) acc[ci][nb] = (f32x4){0.f, 0.f, 0.f, 0.f};

    // staging: one global_load_lds(16B) per thread per chunk
    const uint16_t* srcbase =
        dC + (b * 64 + wid * 16 + (lane >> 2)) * 2048 + jb0 + (lane & 3) * 8;

#define STAGE(n, buf)                                                         \
    __builtin_amdgcn_global_load_lds((glb_t*)(srcbase + (n) * 32),            \
                                     (lds_t*)(&db[buf][wid * 512]), 16, 0, 0)

    STAGE(0, 0);

    for (int n = 0; n < 16; n++) {
        __syncthreads();                      // chunk n staged (vmcnt drained)
        if (n < 15) STAGE(n + 1, (n + 1) & 1);
        const int buf = n & 1;

        // B-frags: dcoef[j=quad*8..+7][c=nb*16+cl]
        B8 bf[4];
#pragma unroll
        for (int nb = 0; nb < 4; nb++)
            bf[nb].u = *(const uint4*)&db[buf][(nb * 16 + cl) * 32 + quad * 8];

        // my 8 pair geometries (pj from L1-hot posT)
        const float4* pp = (const float4*)(posT + b * 2048 + jb0 + n * 32 + quad * 8);
        float4 q0 = pp[0], q1 = pp[1], q2 = pp[2], q3 = pp[3];
        float dxv[8], dyv[8];
        dxv[0] = pI.x - q0.x; dyv[0] = pI.y - q0.y;
        dxv[1] = pI.x - q0.z; dyv[1] = pI.y - q0.w;
        dxv[2] = pI.x - q1.x; dyv[2] = pI.y - q1.y;
        dxv[3] = pI.x - q1.z; dyv[3] = pI.y - q1.w;
        dxv[4] = pI.x - q2.x; dyv[4] = pI.y - q2.y;
        dxv[5] = pI.x - q2.z; dyv[5] = pI.y - q2.w;
        dxv[6] = pI.x - q3.x; dyv[6] = pI.y - q3.y;
        dxv[7] = pI.x - q3.z; dyv[7] = pI.y - q3.w;

#pragma unroll
        for (int ci = 0; ci < 3; ci++) {
            if (ci < nc) {                    // wave-uniform
                float ox = oxr[ci], oy = oyr[ci];
                float w[8];
#pragma unroll
                for (int p = 0; p < 8; p++) {
                    float ax = dxv[p] + ox;
                    float sx = fmaf(-ax, ax, R2);
                    float ay = dyv[p] + oy;
                    float t  = fmaf(-ay, ay, sx);
                    float mt = fmaxf(t, 0.0f);
                    w[p] = (mt * mt) * (mt * KNORM);
                }
                B8 af;
                af.u = make_uint4(pk2(w[0], w[1]), pk2(w[2], w[3]),
                                  pk2(w[4], w[5]), pk2(w[6], w[7]));
#pragma unroll
                for (int nb = 0; nb < 4; nb++)
                    acc[ci][nb] = __builtin_amdgcn_mfma_f32_16x16x32_bf16(
                        af.v, bf[nb].v, acc[ci][nb], 0, 0, 0);
            }
        }
    }

    // ---- GEMM2 per wave: out16x64 partial = sum_{own cells} field_k . W_k --
    float* scr = &sft[wid * (16 * 68)];
    f32x4 acc2[4];
#pragma unroll
    for (int ob = 0; ob < 4; ob++) acc2[ob] = (f32x4){0.f, 0.f, 0.f, 0.f};

#pragma unroll
    for (int ci = 0; ci < 3; ci++) {
        if (ci < nc) {
            // C-frag (row=i=quad*4+r, col=c=nb*16+cl) -> scr[i][c]
#pragma unroll
            for (int nb = 0; nb < 4; nb++)
#pragma unroll
                for (int r = 0; r < 4; r++)
                    scr[(quad * 4 + r) * 68 + nb * 16 + cl] = acc[ci][nb][r];
            // A-frags (m=i=cl, k=c=quad*8+jj) + WB B-frags
            int k = c0 + ci;
#pragma unroll
            for (int ks = 0; ks < 2; ks++) {
                const float* fp = &scr[cl * 68 + ks * 32 + quad * 8];
                float4 lo = *(const float4*)fp;
                float4 hi = *(const float4*)(fp + 4);
                B8 af;
                af.u = make_uint4(pk2(lo.x, lo.y), pk2(lo.z, lo.w),
                                  pk2(hi.x, hi.y), pk2(hi.z, hi.w));
#pragma unroll
                for (int ob = 0; ob < 4; ob++) {
                    B8 wf;
                    wf.u = *(const uint4*)(WB + k * 4096 + (ks * 4 + ob) * 512 + lane * 8);
                    acc2[ob] = __builtin_amdgcn_mfma_f32_16x16x32_bf16(
                        af.v, wf.v, acc2[ob], 0, 0, 0);
                }
            }
        }
    }

    __syncthreads();    // everyone done with transpose use of sft
    // acc2 C-frag (row=i=quad*4+r, col=o'=cl; o=ob*16+cl) -> scr[i][o]
#pragma unroll
    for (int ob = 0; ob < 4; ob++)
#pragma unroll
        for (int r = 0; r < 4; r++)
            scr[(quad * 4 + r) * 68 + ob * 16 + cl] = acc2[ob][r];
    __syncthreads();

    // reduce 4 wave-slices, atomically add to out. thread = (og, i)
    {
        const int i  = tid & 15;
        const int og = tid >> 4;              // 16 groups of 4 o
        float4 s0 = *(const float4*)&sft[0 * 1088 + i * 68 + og * 4];
        float4 s1 = *(const float4*)&sft[1 * 1088 + i * 68 + og * 4];
        float4 s2 = *(const float4*)&sft[2 * 1088 + i * 68 + og * 4];
        float4 s3 = *(const float4*)&sft[3 * 1088 + i * 68 + og * 4];
        float v0 = s0.x + s1.x + s2.x + s3.x;
        float v1 = s0.y + s1.y + s2.y + s3.y;
        float v2 = s0.z + s1.z + s2.z + s3.z;
        float v3 = s0.w + s1.w + s2.w + s3.w;
        float* ob_ = out + (b * 64 + og * 4) * 2048 + i0 + i;
        unsafeAtomicAdd(ob_ + 0 * 2048, v0);
        unsafeAtomicAdd(ob_ + 1 * 2048, v1);
        unsafeAtomicAdd(ob_ + 2 * 2048, v2);
        unsafeAtomicAdd(ob_ + 3 * 2048, v3);
    }
#undef STAGE
}

extern "C" void kernel_launch(void* const* d_in, const int* in_sizes, int n_in,
                              void* d_out, int out_size, void* d_ws, size_t ws_size,
                              hipStream_t stream)
{
    const float* locs    = (const float*)d_in[0];   // (B, N, 3)
    const float* data    = (const float*)d_in[1];   // (B, CIN, N)
    const float* density = (const float*)d_in[2];   // (B, N)
    const float* weight  = (const float*)d_in[3];   // (COUT, CIN, 9)
    const float* bias    = (const float*)d_in[4];   // (COUT,)
    float* out = (float*)d_out;                     // (B, COUT, N)

    float2*   posT = (float2*)d_ws;                             // 32768 B
    uint16_t* dC   = (uint16_t*)((char*)d_ws + 32768);          // 524288 B
    uint16_t* WB   = (uint16_t*)((char*)d_ws + 32768 + 524288); // 73728 B

    prep_kernel<<<272 + NCELL + 128, 256, 0, stream>>>(
        locs, data, density, weight, bias, posT, dC, WB, out);
    conv_kernel<<<BATCH * 128 * 4, 256, 0, stream>>>(posT, dC, WB, out);
}